// Round 4
// baseline (754.796 us; speedup 1.0000x reference)
//
#include <hip/hip_runtime.h>

#define N_PTS 1000000

typedef _Float16 f16;
typedef _Float16 f16x2 __attribute__((ext_vector_type(2)));
typedef _Float16 f16x8 __attribute__((ext_vector_type(8)));
typedef float    f32x4 __attribute__((ext_vector_type(4)));

// ws layout (f16 elements), planes channel-last [H][W][32]
#define PXY_C 0
#define PXZ_C 524288
#define PYZ_C 1048576
#define PXY_F 1572864
#define PXZ_F 9961472
#define PYZ_F 18350080
#define PCXY  26738688
#define PCXZ  28835840
#define PCYZ  30932992
#define WBOFF 33030144
#define FIXED_BYTES ((size_t)(WBOFF + 40960) * 2)   // 66,142,208

__device__ __forceinline__ f32x4 mfma16(f16x8 a, f16x8 b, f32x4 c) {
    return __builtin_amdgcn_mfma_f32_16x16x32_f16(a, b, c, 0, 0, 0);
}

#define LDS_FENCE() asm volatile("s_waitcnt lgkmcnt(0)" ::: "memory")

// ---- pre-pass: [32,H,W] f32 -> [H,W,32] f16 (channel-last, 64B per texel)
__global__ void transpose_plane(const float* __restrict__ src, unsigned short* __restrict__ dst, int npix) {
    int pix = blockIdx.x * 256 + threadIdx.x;
    unsigned w[16];
#pragma unroll
    for (int j = 0; j < 16; ++j) {
        f16x2 v = { (f16)src[(size_t)(2*j) * npix + pix], (f16)src[(size_t)(2*j+1) * npix + pix] };
        w[j] = __builtin_bit_cast(unsigned, v);
    }
#pragma unroll
    for (int j = 0; j < 4; ++j) {
        uint4 o; o.x = w[4*j+0]; o.y = w[4*j+1]; o.z = w[4*j+2]; o.w = w[4*j+3];
        *(uint4*)(dst + (size_t)pix * 32 + 8*j) = o;
    }
}

// ---- pre-pass: weights f32 -> f16
__global__ void f32_to_f16_k(const float* __restrict__ src, unsigned short* __restrict__ dst, int n) {
    int i = blockIdx.x * 256 + threadIdx.x;
    if (i < n) { f16 h = (f16)src[i]; dst[i] = __builtin_bit_cast(unsigned short, h); }
}

// ---- coalesced 3-plane bilinear gather, one 64-pt tile.
// lane = (sub=lane>>2 -> point, ch=lane&3 -> 8-ch slice); 4 rounds x 16 points.
// WRITE: store to LDS [64][32] f16, rows 64B, XOR swizzle (row&3)<<4.
// !WRITE: return packed rows in ov[4] (writes deferred by caller).
template <bool WRITE>
__device__ __forceinline__ void gather3(
    const unsigned short* __restrict__ P0, const unsigned short* __restrict__ P1,
    const unsigned short* __restrict__ P2, int R,
    const float* __restrict__ p, int ptbase, int lane,
    unsigned short* dst, uint4* ov) {
    const int sub = lane >> 2, ch = lane & 3;
    const float Rs = 0.5f * (float)(R - 1);
#pragma unroll
    for (int r = 0; r < 4; ++r) {
        const int row = r * 16 + sub;
        const float* pp = p + 3 * (size_t)(ptbase + row);
        const float pa = pp[0], pb = pp[1], pc = pp[2];
        f16x2 a0 = {0,0}, a1 = {0,0}, a2 = {0,0}, a3 = {0,0};
        const float cA[3] = {pa, pa, pb};
        const float cB[3] = {pb, pc, pc};
        const unsigned short* tp[3] = {P0, P1, P2};
#pragma unroll
        for (int pl = 0; pl < 3; ++pl) {
            float x = (cA[pl] + 1.0f) * Rs;
            float y = (cB[pl] + 1.0f) * Rs;
            float fx = floorf(x), fy = floorf(y);
            float wx = x - fx, wy = y - fy;
            int x0 = min(max((int)fx, 0), R - 1);
            int x1 = min(x0 + 1, R - 1);
            int y0 = min(max((int)fy, 0), R - 1);
            int y1 = min(y0 + 1, R - 1);
            const unsigned short* b = tp[pl];
            uint4 v00 = *(const uint4*)(b + (size_t)(y0 * R + x0) * 32 + ch * 8);
            uint4 v01 = *(const uint4*)(b + (size_t)(y0 * R + x1) * 32 + ch * 8);
            uint4 v10 = *(const uint4*)(b + (size_t)(y1 * R + x0) * 32 + ch * 8);
            uint4 v11 = *(const uint4*)(b + (size_t)(y1 * R + x1) * 32 + ch * 8);
            f16 h00 = (f16)((1.0f - wx) * (1.0f - wy));
            f16 h01 = (f16)(wx * (1.0f - wy));
            f16 h10 = (f16)((1.0f - wx) * wy);
            f16 h11 = (f16)(wx * wy);
            f16x2 w00 = {h00, h00}, w01 = {h01, h01}, w10 = {h10, h10}, w11 = {h11, h11};
            a0 += __builtin_bit_cast(f16x2, v00.x) * w00 + __builtin_bit_cast(f16x2, v01.x) * w01
                + __builtin_bit_cast(f16x2, v10.x) * w10 + __builtin_bit_cast(f16x2, v11.x) * w11;
            a1 += __builtin_bit_cast(f16x2, v00.y) * w00 + __builtin_bit_cast(f16x2, v01.y) * w01
                + __builtin_bit_cast(f16x2, v10.y) * w10 + __builtin_bit_cast(f16x2, v11.y) * w11;
            a2 += __builtin_bit_cast(f16x2, v00.z) * w00 + __builtin_bit_cast(f16x2, v01.z) * w01
                + __builtin_bit_cast(f16x2, v10.z) * w10 + __builtin_bit_cast(f16x2, v11.z) * w11;
            a3 += __builtin_bit_cast(f16x2, v00.w) * w00 + __builtin_bit_cast(f16x2, v01.w) * w01
                + __builtin_bit_cast(f16x2, v10.w) * w10 + __builtin_bit_cast(f16x2, v11.w) * w11;
        }
        uint4 o;
        o.x = __builtin_bit_cast(unsigned, a0);
        o.y = __builtin_bit_cast(unsigned, a1);
        o.z = __builtin_bit_cast(unsigned, a2);
        o.w = __builtin_bit_cast(unsigned, a3);
        if (WRITE) {
            *(uint4*)((char*)dst + row * 64 + ((ch * 16) ^ ((row & 3) << 4))) = o;
        } else {
            ov[r] = o;
        }
    }
}

// A-frag loads from swizzled LDS: rows RSb bytes, element k=8q0+j+32ks at byte 16q0+64ks
template <int KT, int SWA>
__device__ __forceinline__ void ldA(f16x8 (&A)[4][KT], const char* src, int RSb, int c0, int q0) {
#pragma unroll
    for (int mt = 0; mt < 4; ++mt) {
        const int row = 16 * mt + c0;
#pragma unroll
        for (int ks = 0; ks < KT; ++ks)
            A[mt][ks] = *(const f16x8*)(src + row * RSb + ((16*q0 + 64*ks) ^ ((row & SWA) << 4)));
    }
}

// GEMM: A (regs) x W[N][K] (global f16) -> relu -> LDS, swizzle (row&7)<<4
template <int KT, int NT>
__device__ __forceinline__ void gemm_store(const f16x8 (&A)[4][KT], char* O, int RSOb,
                                           const unsigned short* __restrict__ Wg, int K,
                                           const float* __restrict__ bias, int c0, int q0) {
#pragma unroll
    for (int nt = 0; nt < NT; ++nt) {
        f16x8 B[KT];
#pragma unroll
        for (int ks = 0; ks < KT; ++ks)
            B[ks] = *(const f16x8*)(Wg + (size_t)(16*nt + c0) * K + 8*q0 + 32*ks);
        const float bv = bias[16*nt + c0];
#pragma unroll
        for (int mt = 0; mt < 4; ++mt) {
            f32x4 acc = {0.f, 0.f, 0.f, 0.f};
#pragma unroll
            for (int ks = 0; ks < KT; ++ks) acc = mfma16(A[mt][ks], B[ks], acc);
#pragma unroll
            for (int i = 0; i < 4; ++i) {
                const f16 v = (f16)fmaxf(acc[i] + bv, 0.0f);
                const int row = 16*mt + 4*q0 + i;
                *(f16*)(O + row * RSOb + ((2*(16*nt + c0)) ^ ((row & 7) << 4))) = v;
            }
        }
    }
}

__global__ __launch_bounds__(128, 3) void decoder_main(
    const float* __restrict__ p,
    const unsigned short* __restrict__ ws,
    const float* __restrict__ lin0_b, const float* __restrict__ lin1_b,
    const float* __restrict__ comb0_b, const float* __restrict__ comb1_b,
    const float* __restrict__ out_w, const float* __restrict__ out_b,
    const float* __restrict__ clin0_b, const float* __restrict__ clin1_b,
    const float* __restrict__ cout_w, const float* __restrict__ cout_b,
    float* __restrict__ out) {
    __shared__ __align__(16) unsigned short lds[2][8192];   // 16 KB per wave
    const int tid = threadIdx.x;
    const int wave = tid >> 6, lane = tid & 63;
    const int c0 = lane & 15, q0 = lane >> 4;
    const int pbase = blockIdx.x * 128 + wave * 64;
    if (pbase >= N_PTS) return;
    char* L = (char*)lds[wave];

    const unsigned short* WB  = ws + WBOFF;   // f16 weights
    const unsigned short* W0  = WB;           // [64][32]
    const unsigned short* W1  = WB + 2048;    // [64][64]
    const unsigned short* WC0 = WB + 6144;    // [128][96]
    const unsigned short* WC1 = WB + 18432;   // [128][128]
    const unsigned short* WL0 = WB + 34816;   // [64][32]
    const unsigned short* WL1 = WB + 36864;   // [64][64]

    // LDS byte map per wave: FEATC@0 (4K) | H0@4096 (8K, rows 128B) | H1@0 (8K) |
    // FEATF@12288 (4K) | H2@0 (16K, rows 256B) | FEATC2@0 | HC0@4096 | reduce@0 (16K)

    // coarse + fine gathers upfront (fine latency hides under lin0/lin1)
    gather3<true>(ws + PXY_C, ws + PXZ_C, ws + PYZ_C, 128, p, pbase, lane,
                  (unsigned short*)L, nullptr);
    gather3<true>(ws + PXY_F, ws + PXZ_F, ws + PYZ_F, 512, p, pbase, lane,
                  (unsigned short*)(L + 12288), nullptr);
    LDS_FENCE();

    // lin0: K=32, FEATC -> H0
    {
        f16x8 A[4][1];
        ldA<1, 3>(A, L, 64, c0, q0);
        gemm_store<1, 4>(A, L + 4096, 128, W0, 32, lin0_b, c0, q0);
    }
    LDS_FENCE();
    // lin1: K=64, H0 -> H1 (regions overlap: A fully cached before stores)
    {
        f16x8 A[4][2];
        ldA<2, 7>(A, L + 4096, 128, c0, q0);
        LDS_FENCE();
        gemm_store<2, 4>(A, L, 128, W1, 64, lin1_b, c0, q0);
    }
    LDS_FENCE();
    // comb0: A=[H1 | FEATF], K=96 -> H2 (overlaps both: A cached first)
    {
        f16x8 A[4][3];
#pragma unroll
        for (int mt = 0; mt < 4; ++mt) {
            const int row = 16*mt + c0;
#pragma unroll
            for (int ks = 0; ks < 2; ++ks)
                A[mt][ks] = *(const f16x8*)(L + row * 128 + ((16*q0 + 64*ks) ^ ((row & 7) << 4)));
            A[mt][2] = *(const f16x8*)(L + 12288 + row * 64 + ((16*q0) ^ ((row & 3) << 4)));
        }
        LDS_FENCE();
        gemm_store<3, 8>(A, L, 256, WC0, 96, comb0_b, c0, q0);
    }
    LDS_FENCE();

    // color gather: loads+interp now (overlap comb1), LDS writes deferred (comb1 reads all of H2)
    uint4 cov[4];
    gather3<false>(ws + PCXY, ws + PCXZ, ws + PCYZ, 256, p, pbase, lane, nullptr, cov);

    // comb1: K=128, streamed A from H2 (no LDS writes -> no WAR), fused sdf fold
    float part[16];
#pragma unroll
    for (int r = 0; r < 16; ++r) part[r] = 0.f;
#pragma unroll
    for (int nt = 0; nt < 8; ++nt) {
        f16x8 B[4];
#pragma unroll
        for (int ks = 0; ks < 4; ++ks)
            B[ks] = *(const f16x8*)(WC1 + (size_t)(16*nt + c0) * 128 + 8*q0 + 32*ks);
        const float bv = comb1_b[16*nt + c0];
        const float wo = out_w[16*nt + c0];
#pragma unroll
        for (int mt = 0; mt < 4; ++mt) {
            const int row = 16*mt + c0;
            f16x8 a[4];
#pragma unroll
            for (int ks = 0; ks < 4; ++ks)
                a[ks] = *(const f16x8*)(L + row * 256 + ((16*q0 + 64*ks) ^ ((row & 7) << 4)));
            f32x4 acc = {0.f, 0.f, 0.f, 0.f};
#pragma unroll
            for (int ks = 0; ks < 4; ++ks) acc = mfma16(a[ks], B[ks], acc);
#pragma unroll
            for (int i = 0; i < 4; ++i)
                part[4*mt + i] += wo * fmaxf(acc[i] + bv, 0.0f);
        }
    }
    LDS_FENCE();
    // deferred color-feat writes -> FEATC2@0
    {
        const int sub = lane >> 2, ch = lane & 3;
#pragma unroll
        for (int r = 0; r < 4; ++r) {
            const int row = r * 16 + sub;
            *(uint4*)(L + row * 64 + ((ch * 16) ^ ((row & 3) << 4))) = cov[r];
        }
    }
    LDS_FENCE();

    // clin0: K=32, FEATC2 -> HC0@4096 (disjoint regions)
    {
        f16x8 A[4][1];
        ldA<1, 3>(A, L, 64, c0, q0);
        gemm_store<1, 4>(A, L + 4096, 128, WL0, 32, clin0_b, c0, q0);
    }
    LDS_FENCE();
    // clin1: K=64, fused cout fold
    float pc0[16], pc1[16], pc2[16];
#pragma unroll
    for (int r = 0; r < 16; ++r) { pc0[r] = 0.f; pc1[r] = 0.f; pc2[r] = 0.f; }
    {
        f16x8 A[4][2];
        ldA<2, 7>(A, L + 4096, 128, c0, q0);
        LDS_FENCE();
#pragma unroll
        for (int nt = 0; nt < 4; ++nt) {
            f16x8 B[2];
#pragma unroll
            for (int ks = 0; ks < 2; ++ks)
                B[ks] = *(const f16x8*)(WL1 + (size_t)(16*nt + c0) * 64 + 8*q0 + 32*ks);
            const float bv  = clin1_b[16*nt + c0];
            const float cw0 = cout_w[16*nt + c0];
            const float cw1 = cout_w[64 + 16*nt + c0];
            const float cw2 = cout_w[128 + 16*nt + c0];
#pragma unroll
            for (int mt = 0; mt < 4; ++mt) {
                f32x4 acc = {0.f, 0.f, 0.f, 0.f};
#pragma unroll
                for (int ks = 0; ks < 2; ++ks) acc = mfma16(A[mt][ks], B[ks], acc);
#pragma unroll
                for (int i = 0; i < 4; ++i) {
                    const float hv = fmaxf(acc[i] + bv, 0.0f);
                    pc0[4*mt+i] += cw0 * hv;
                    pc1[4*mt+i] += cw1 * hv;
                    pc2[4*mt+i] += cw2 * hv;
                }
            }
        }
    }

    // epilogue: LDS transpose-reduce over the 16 c0 lanes, coalesced float4 store
#pragma unroll
    for (int mt = 0; mt < 4; ++mt)
#pragma unroll
        for (int i = 0; i < 4; ++i) {
            const int r = 4*mt + i;
            const int row = 16*mt + 4*q0 + i;
            float4 v; v.x = pc0[r]; v.y = pc1[r]; v.z = pc2[r]; v.w = part[r];
            *(float4*)(L + row * 256 + ((c0 * 16) ^ ((row & 7) << 4))) = v;
        }
    LDS_FENCE();
    {
        float4 s; s.x = 0.f; s.y = 0.f; s.z = 0.f; s.w = 0.f;
#pragma unroll
        for (int c = 0; c < 16; ++c) {
            float4 v = *(const float4*)(L + lane * 256 + ((c * 16) ^ ((lane & 7) << 4)));
            s.x += v.x; s.y += v.y; s.z += v.z; s.w += v.w;
        }
        float4 o;
        o.x = 1.0f / (1.0f + __expf(-(s.x + cout_b[0])));
        o.y = 1.0f / (1.0f + __expf(-(s.y + cout_b[1])));
        o.z = 1.0f / (1.0f + __expf(-(s.z + cout_b[2])));
        o.w = s.w + out_b[0];
        *(float4*)(out + 4 * (size_t)(pbase + lane)) = o;
    }
}

extern "C" void kernel_launch(void* const* d_in, const int* in_sizes, int n_in,
                              void* d_out, int out_size, void* d_ws, size_t ws_size,
                              hipStream_t stream) {
    if (ws_size < FIXED_BYTES) return;
    unsigned short* ws = (unsigned short*)d_ws;

    static const int    npix[9] = {16384,16384,16384,262144,262144,262144,65536,65536,65536};
    static const size_t poff[9] = {PXY_C,PXZ_C,PYZ_C,PXY_F,PXZ_F,PYZ_F,PCXY,PCXZ,PCYZ};
    for (int i = 0; i < 9; ++i)
        transpose_plane<<<npix[i]/256, 256, 0, stream>>>((const float*)d_in[1+i], ws + poff[i], npix[i]);

    static const int    widx[6] = {10,12,14,16,20,22};   // lin0_w,lin1_w,comb0_w,comb1_w,clin0_w,clin1_w
    static const int    wn[6]   = {2048,4096,12288,16384,2048,4096};
    static const size_t woff[6] = {0,2048,6144,18432,34816,36864};
    unsigned short* wb = ws + WBOFF;
    for (int i = 0; i < 6; ++i)
        f32_to_f16_k<<<(wn[i]+255)/256, 256, 0, stream>>>((const float*)d_in[widx[i]], wb + woff[i], wn[i]);

    decoder_main<<<(N_PTS/64 + 1)/2, 128, 0, stream>>>(
        (const float*)d_in[0], ws,
        (const float*)d_in[11], (const float*)d_in[13],
        (const float*)d_in[15], (const float*)d_in[17],
        (const float*)d_in[18], (const float*)d_in[19],
        (const float*)d_in[21], (const float*)d_in[23],
        (const float*)d_in[24], (const float*)d_in[25],
        (float*)d_out);
}

// Round 5
// 689.510 us; speedup vs baseline: 1.0947x; 1.0947x over previous
//
#include <hip/hip_runtime.h>

#define N_PTS 1000000

typedef _Float16 f16;
typedef _Float16 f16x2 __attribute__((ext_vector_type(2)));
typedef _Float16 f16x8 __attribute__((ext_vector_type(8)));
typedef float    f32x4 __attribute__((ext_vector_type(4)));

// ws layout (f16 elements), planes channel-last [H][W][32]
#define PXY_C 0
#define PXZ_C 524288
#define PYZ_C 1048576
#define PXY_F 1572864
#define PXZ_F 9961472
#define PYZ_F 18350080
#define PCXY  26738688
#define PCXZ  28835840
#define PCYZ  30932992
#define WBOFF 33030144
#define FIXED_BYTES ((size_t)(WBOFF + 40960) * 2)   // 66,142,208

__device__ __forceinline__ f32x4 mfma16(f16x8 a, f16x8 b, f32x4 c) {
    return __builtin_amdgcn_mfma_f32_16x16x32_f16(a, b, c, 0, 0, 0);
}

#define LDS_FENCE() asm volatile("s_waitcnt lgkmcnt(0)" ::: "memory")

// ---- pre-pass: [32,H,W] f32 -> [H,W,32] f16 (channel-last, 64B per texel)
__global__ void transpose_plane(const float* __restrict__ src, unsigned short* __restrict__ dst, int npix) {
    int pix = blockIdx.x * 256 + threadIdx.x;
    unsigned w[16];
#pragma unroll
    for (int j = 0; j < 16; ++j) {
        f16x2 v = { (f16)src[(size_t)(2*j) * npix + pix], (f16)src[(size_t)(2*j+1) * npix + pix] };
        w[j] = __builtin_bit_cast(unsigned, v);
    }
#pragma unroll
    for (int j = 0; j < 4; ++j) {
        uint4 o; o.x = w[4*j+0]; o.y = w[4*j+1]; o.z = w[4*j+2]; o.w = w[4*j+3];
        *(uint4*)(dst + (size_t)pix * 32 + 8*j) = o;
    }
}

// ---- pre-pass: weights f32 -> f16
__global__ void f32_to_f16_k(const float* __restrict__ src, unsigned short* __restrict__ dst, int n) {
    int i = blockIdx.x * 256 + threadIdx.x;
    if (i < n) { f16 h = (f16)src[i]; dst[i] = __builtin_bit_cast(unsigned short, h); }
}

// ---- coalesced 3-plane bilinear gather, one 64-pt tile.
// lane = (sub=lane>>2 -> point, ch=lane&3 -> 8-ch slice); 4 rounds x 16 points.
// Stores to LDS [64][32] f16, rows 64B, XOR swizzle (row&3)<<4.
__device__ __forceinline__ void gather3(
    const unsigned short* __restrict__ P0, const unsigned short* __restrict__ P1,
    const unsigned short* __restrict__ P2, int R,
    const float* __restrict__ p, int ptbase, int lane, char* dst) {
    const int sub = lane >> 2, ch = lane & 3;
    const float Rs = 0.5f * (float)(R - 1);
#pragma unroll
    for (int r = 0; r < 4; ++r) {
        const int row = r * 16 + sub;
        const float* pp = p + 3 * (size_t)(ptbase + row);
        const float pa = pp[0], pb = pp[1], pc = pp[2];
        f16x2 a0 = {0,0}, a1 = {0,0}, a2 = {0,0}, a3 = {0,0};
        const float cA[3] = {pa, pa, pb};
        const float cB[3] = {pb, pc, pc};
        const unsigned short* tp[3] = {P0, P1, P2};
#pragma unroll
        for (int pl = 0; pl < 3; ++pl) {
            float x = (cA[pl] + 1.0f) * Rs;
            float y = (cB[pl] + 1.0f) * Rs;
            float fx = floorf(x), fy = floorf(y);
            float wx = x - fx, wy = y - fy;
            int x0 = min(max((int)fx, 0), R - 1);
            int x1 = min(x0 + 1, R - 1);
            int y0 = min(max((int)fy, 0), R - 1);
            int y1 = min(y0 + 1, R - 1);
            const unsigned short* b = tp[pl];
            uint4 v00 = *(const uint4*)(b + (size_t)(y0 * R + x0) * 32 + ch * 8);
            uint4 v01 = *(const uint4*)(b + (size_t)(y0 * R + x1) * 32 + ch * 8);
            uint4 v10 = *(const uint4*)(b + (size_t)(y1 * R + x0) * 32 + ch * 8);
            uint4 v11 = *(const uint4*)(b + (size_t)(y1 * R + x1) * 32 + ch * 8);
            f16 h00 = (f16)((1.0f - wx) * (1.0f - wy));
            f16 h01 = (f16)(wx * (1.0f - wy));
            f16 h10 = (f16)((1.0f - wx) * wy);
            f16 h11 = (f16)(wx * wy);
            f16x2 w00 = {h00, h00}, w01 = {h01, h01}, w10 = {h10, h10}, w11 = {h11, h11};
            a0 += __builtin_bit_cast(f16x2, v00.x) * w00 + __builtin_bit_cast(f16x2, v01.x) * w01
                + __builtin_bit_cast(f16x2, v10.x) * w10 + __builtin_bit_cast(f16x2, v11.x) * w11;
            a1 += __builtin_bit_cast(f16x2, v00.y) * w00 + __builtin_bit_cast(f16x2, v01.y) * w01
                + __builtin_bit_cast(f16x2, v10.y) * w10 + __builtin_bit_cast(f16x2, v11.y) * w11;
            a2 += __builtin_bit_cast(f16x2, v00.z) * w00 + __builtin_bit_cast(f16x2, v01.z) * w01
                + __builtin_bit_cast(f16x2, v10.z) * w10 + __builtin_bit_cast(f16x2, v11.z) * w11;
            a3 += __builtin_bit_cast(f16x2, v00.w) * w00 + __builtin_bit_cast(f16x2, v01.w) * w01
                + __builtin_bit_cast(f16x2, v10.w) * w10 + __builtin_bit_cast(f16x2, v11.w) * w11;
        }
        uint4 o;
        o.x = __builtin_bit_cast(unsigned, a0);
        o.y = __builtin_bit_cast(unsigned, a1);
        o.z = __builtin_bit_cast(unsigned, a2);
        o.w = __builtin_bit_cast(unsigned, a3);
        *(uint4*)(dst + row * 64 + ((ch * 16) ^ ((row & 3) << 4))) = o;
    }
}

// A-frag loads from swizzled LDS: rows RSb bytes, element k=8q0+j+32ks at byte 16q0+64ks
template <int KT, int SWA>
__device__ __forceinline__ void ldA(f16x8 (&A)[4][KT], const char* src, int RSb, int c0, int q0) {
#pragma unroll
    for (int mt = 0; mt < 4; ++mt) {
        const int row = 16 * mt + c0;
#pragma unroll
        for (int ks = 0; ks < KT; ++ks)
            A[mt][ks] = *(const f16x8*)(src + row * RSb + ((16*q0 + 64*ks) ^ ((row & SWA) << 4)));
    }
}

// GEMM: A (regs) x W[N][K] (global f16) -> relu -> LDS, swizzle (row&7)<<4
template <int KT, int NT>
__device__ __forceinline__ void gemm_store(const f16x8 (&A)[4][KT], char* O, int RSOb,
                                           const unsigned short* __restrict__ Wg, int K,
                                           const float* __restrict__ bias, int c0, int q0) {
#pragma unroll
    for (int nt = 0; nt < NT; ++nt) {
        f16x8 B[KT];
#pragma unroll
        for (int ks = 0; ks < KT; ++ks)
            B[ks] = *(const f16x8*)(Wg + (size_t)(16*nt + c0) * K + 8*q0 + 32*ks);
        const float bv = bias[16*nt + c0];
#pragma unroll
        for (int mt = 0; mt < 4; ++mt) {
            f32x4 acc = {0.f, 0.f, 0.f, 0.f};
#pragma unroll
            for (int ks = 0; ks < KT; ++ks) acc = mfma16(A[mt][ks], B[ks], acc);
#pragma unroll
            for (int i = 0; i < 4; ++i) {
                const f16 v = (f16)fmaxf(acc[i] + bv, 0.0f);
                const int row = 16*mt + 4*q0 + i;
                *(f16*)(O + row * RSOb + ((2*(16*nt + c0)) ^ ((row & 7) << 4))) = v;
            }
        }
    }
}

__global__ __launch_bounds__(128) void decoder_main(
    const float* __restrict__ p,
    const unsigned short* __restrict__ ws,
    const float* __restrict__ lin0_b, const float* __restrict__ lin1_b,
    const float* __restrict__ comb0_b, const float* __restrict__ comb1_b,
    const float* __restrict__ out_w, const float* __restrict__ out_b,
    const float* __restrict__ clin0_b, const float* __restrict__ clin1_b,
    const float* __restrict__ cout_w, const float* __restrict__ cout_b,
    float* __restrict__ out) {
    __shared__ __align__(16) unsigned short lds[2][8192];   // 16 KB per wave
    const int tid = threadIdx.x;
    const int wave = tid >> 6, lane = tid & 63;
    const int c0 = lane & 15, q0 = lane >> 4;
    const int pbase = blockIdx.x * 128 + wave * 64;
    if (pbase >= N_PTS) return;
    char* L = (char*)lds[wave];

    const unsigned short* WB  = ws + WBOFF;   // f16 weights
    const unsigned short* W0  = WB;           // [64][32]
    const unsigned short* W1  = WB + 2048;    // [64][64]
    const unsigned short* WC0 = WB + 6144;    // [128][96]
    const unsigned short* WC1 = WB + 18432;   // [128][128]
    const unsigned short* WL0 = WB + 34816;   // [64][32]
    const unsigned short* WL1 = WB + 36864;   // [64][64]

    // LDS byte map per wave: FEATC@0 (4K) | H0@4096 (8K, rows 128B) | H1@0 (8K) |
    // FEATF@12288 (4K) | H2@0 (16K, rows 256B) | FEATC2@0 | HC0@4096 | reduce@0 (16K)

    // coarse + fine gathers upfront (fine latency hides under lin0/lin1)
    gather3(ws + PXY_C, ws + PXZ_C, ws + PYZ_C, 128, p, pbase, lane, L);
    gather3(ws + PXY_F, ws + PXZ_F, ws + PYZ_F, 512, p, pbase, lane, L + 12288);
    LDS_FENCE();

    // lin0: K=32, FEATC -> H0
    {
        f16x8 A[4][1];
        ldA<1, 3>(A, L, 64, c0, q0);
        gemm_store<1, 4>(A, L + 4096, 128, W0, 32, lin0_b, c0, q0);
    }
    LDS_FENCE();
    // lin1: K=64, H0 -> H1 (regions overlap: A fully cached before stores)
    {
        f16x8 A[4][2];
        ldA<2, 7>(A, L + 4096, 128, c0, q0);
        LDS_FENCE();
        gemm_store<2, 4>(A, L, 128, W1, 64, lin1_b, c0, q0);
    }
    LDS_FENCE();
    // comb0: A=[H1 | FEATF], K=96 -> H2 (overlaps both: A cached first)
    {
        f16x8 A[4][3];
#pragma unroll
        for (int mt = 0; mt < 4; ++mt) {
            const int row = 16*mt + c0;
#pragma unroll
            for (int ks = 0; ks < 2; ++ks)
                A[mt][ks] = *(const f16x8*)(L + row * 128 + ((16*q0 + 64*ks) ^ ((row & 7) << 4)));
            A[mt][2] = *(const f16x8*)(L + 12288 + row * 64 + ((16*q0) ^ ((row & 3) << 4)));
        }
        LDS_FENCE();
        gemm_store<3, 8>(A, L, 256, WC0, 96, comb0_b, c0, q0);
    }
    LDS_FENCE();

    // comb1: K=128, A[4][4] cached up-front; color gather overlapped under the MFMAs,
    // writing FEATC2@0 directly (A fully in regs; per-wave DS ordering + fence = safe)
    float part[16];
#pragma unroll
    for (int r = 0; r < 16; ++r) part[r] = 0.f;
    {
        f16x8 A[4][4];
        ldA<4, 7>(A, L, 256, c0, q0);
        LDS_FENCE();
        gather3(ws + PCXY, ws + PCXZ, ws + PCYZ, 256, p, pbase, lane, L);
#pragma unroll
        for (int nt = 0; nt < 8; ++nt) {
            f16x8 B[4];
#pragma unroll
            for (int ks = 0; ks < 4; ++ks)
                B[ks] = *(const f16x8*)(WC1 + (size_t)(16*nt + c0) * 128 + 8*q0 + 32*ks);
            const float bv = comb1_b[16*nt + c0];
            const float wo = out_w[16*nt + c0];
#pragma unroll
            for (int mt = 0; mt < 4; ++mt) {
                f32x4 acc = {0.f, 0.f, 0.f, 0.f};
#pragma unroll
                for (int ks = 0; ks < 4; ++ks) acc = mfma16(A[mt][ks], B[ks], acc);
#pragma unroll
                for (int i = 0; i < 4; ++i)
                    part[4*mt + i] += wo * fmaxf(acc[i] + bv, 0.0f);
            }
        }
    }
    LDS_FENCE();

    // clin0: K=32, FEATC2@0 -> HC0@4096 (disjoint regions)
    {
        f16x8 A[4][1];
        ldA<1, 3>(A, L, 64, c0, q0);
        gemm_store<1, 4>(A, L + 4096, 128, WL0, 32, clin0_b, c0, q0);
    }
    LDS_FENCE();
    // clin1: K=64, fused cout fold
    float pc0[16], pc1[16], pc2[16];
#pragma unroll
    for (int r = 0; r < 16; ++r) { pc0[r] = 0.f; pc1[r] = 0.f; pc2[r] = 0.f; }
    {
        f16x8 A[4][2];
        ldA<2, 7>(A, L + 4096, 128, c0, q0);
        LDS_FENCE();
#pragma unroll
        for (int nt = 0; nt < 4; ++nt) {
            f16x8 B[2];
#pragma unroll
            for (int ks = 0; ks < 2; ++ks)
                B[ks] = *(const f16x8*)(WL1 + (size_t)(16*nt + c0) * 64 + 8*q0 + 32*ks);
            const float bv  = clin1_b[16*nt + c0];
            const float cw0 = cout_w[16*nt + c0];
            const float cw1 = cout_w[64 + 16*nt + c0];
            const float cw2 = cout_w[128 + 16*nt + c0];
#pragma unroll
            for (int mt = 0; mt < 4; ++mt) {
                f32x4 acc = {0.f, 0.f, 0.f, 0.f};
#pragma unroll
                for (int ks = 0; ks < 2; ++ks) acc = mfma16(A[mt][ks], B[ks], acc);
#pragma unroll
                for (int i = 0; i < 4; ++i) {
                    const float hv = fmaxf(acc[i] + bv, 0.0f);
                    pc0[4*mt+i] += cw0 * hv;
                    pc1[4*mt+i] += cw1 * hv;
                    pc2[4*mt+i] += cw2 * hv;
                }
            }
        }
    }

    // epilogue: LDS transpose-reduce over the 16 c0 lanes, coalesced float4 store
#pragma unroll
    for (int mt = 0; mt < 4; ++mt)
#pragma unroll
        for (int i = 0; i < 4; ++i) {
            const int r = 4*mt + i;
            const int row = 16*mt + 4*q0 + i;
            float4 v; v.x = pc0[r]; v.y = pc1[r]; v.z = pc2[r]; v.w = part[r];
            *(float4*)(L + row * 256 + ((c0 * 16) ^ ((row & 7) << 4))) = v;
        }
    LDS_FENCE();
    {
        float4 s; s.x = 0.f; s.y = 0.f; s.z = 0.f; s.w = 0.f;
#pragma unroll
        for (int c = 0; c < 16; ++c) {
            float4 v = *(const float4*)(L + lane * 256 + ((c * 16) ^ ((lane & 7) << 4)));
            s.x += v.x; s.y += v.y; s.z += v.z; s.w += v.w;
        }
        float4 o;
        o.x = 1.0f / (1.0f + __expf(-(s.x + cout_b[0])));
        o.y = 1.0f / (1.0f + __expf(-(s.y + cout_b[1])));
        o.z = 1.0f / (1.0f + __expf(-(s.z + cout_b[2])));
        o.w = s.w + out_b[0];
        *(float4*)(out + 4 * (size_t)(pbase + lane)) = o;
    }
}

extern "C" void kernel_launch(void* const* d_in, const int* in_sizes, int n_in,
                              void* d_out, int out_size, void* d_ws, size_t ws_size,
                              hipStream_t stream) {
    if (ws_size < FIXED_BYTES) return;
    unsigned short* ws = (unsigned short*)d_ws;

    static const int    npix[9] = {16384,16384,16384,262144,262144,262144,65536,65536,65536};
    static const size_t poff[9] = {PXY_C,PXZ_C,PYZ_C,PXY_F,PXZ_F,PYZ_F,PCXY,PCXZ,PCYZ};
    for (int i = 0; i < 9; ++i)
        transpose_plane<<<npix[i]/256, 256, 0, stream>>>((const float*)d_in[1+i], ws + poff[i], npix[i]);

    static const int    widx[6] = {10,12,14,16,20,22};   // lin0_w,lin1_w,comb0_w,comb1_w,clin0_w,clin1_w
    static const int    wn[6]   = {2048,4096,12288,16384,2048,4096};
    static const size_t woff[6] = {0,2048,6144,18432,34816,36864};
    unsigned short* wb = ws + WBOFF;
    for (int i = 0; i < 6; ++i)
        f32_to_f16_k<<<(wn[i]+255)/256, 256, 0, stream>>>((const float*)d_in[widx[i]], wb + woff[i], wn[i]);

    decoder_main<<<(N_PTS/64 + 1)/2, 128, 0, stream>>>(
        (const float*)d_in[0], ws,
        (const float*)d_in[11], (const float*)d_in[13],
        (const float*)d_in[15], (const float*)d_in[17],
        (const float*)d_in[18], (const float*)d_in[19],
        (const float*)d_in[21], (const float*)d_in[23],
        (const float*)d_in[24], (const float*)d_in[25],
        (float*)d_out);
}